// Round 10
// baseline (333.213 us; speedup 1.0000x reference)
//
#include <hip/hip_runtime.h>

typedef _Float16 half8 __attribute__((ext_vector_type(8)));
typedef _Float16 half4 __attribute__((ext_vector_type(4)));
typedef float f32x4 __attribute__((ext_vector_type(4)));

#define HID 512
#define NCHUNK 2048
#define CPB 8       // chunks per persistent block
#define NBLK (NCHUNK / CPB)

// Repack conv_w [O=512][I=512][tap=2] fp32 -> MFMA-fragment-ordered fp16:
// Wf[((nt*32 + ks)*64 + lane)*8 + j] = W[n = nt*16 + (lane&15)][k = ks*32 + (lane>>4)*8 + j]
// where k = tap*512 + i. One 16x16x32 B-fragment = 1KB contiguous.
__global__ void prep_w_kernel(const float* __restrict__ conv_w, _Float16* __restrict__ Wf) {
  int o = blockIdx.x * blockDim.x + threadIdx.x;
  if (o >= HID * HID * 2) return;
  int j = o & 7;
  int lane = (o >> 3) & 63;
  int ks = (o >> 9) & 31;
  int nt = o >> 14;
  int n = nt * 16 + (lane & 15);
  int k = ks * 32 + (lane >> 4) * 8 + j;
  int tap = k >> 9;
  int i = k & 511;
  Wf[o] = (_Float16)conv_w[n * 1024 + i * 2 + tap];
}

// Persistent: CPB chunks per block, 512 threads = 8 waves, 1 block/CU.
// Unified reg budget at 2 waves/SIMD = 256/wave. ONE accumulator (acc) serves
// both conv and PV (PV re-zeros it after the ctT write) -> 64 AGPR, leaving
// ~190 VGPRs for the two 32-reg x-prefetch halves + W pipeline. r4-r8 spilled
// because conv-acc and PV-acc were separate (128 AGPR) + prefetch > 256.
// LDS XOR swizzle on row-major tiles: byte ^= ((row&7)<<4).
__global__ __launch_bounds__(512) void fused_kernel(
    const float* __restrict__ x, const _Float16* __restrict__ Wf,
    const float* __restrict__ conv_b, const float* __restrict__ ln_g,
    const float* __restrict__ ln_b, float* __restrict__ out) {

  // xs: storage row s holds x[s-1]; rows 0 and 65 zero (conv boundary), written once.
  // ct: [key][d] after conv; after scores it is dead and reused as ctT[512 d][64 key].
  __shared__ __align__(16) _Float16 xs[66 * 512];
  __shared__ __align__(16) _Float16 ct[64 * 512];
  __shared__ __align__(16) float sc[64 * 64];       // scores^T staging, granule-swizzled
  __shared__ __align__(16) _Float16 P[64 * 64];     // softmax + I, swizzled
  __shared__ float rowpart[64 * 8 * 2];
  __shared__ float mustat[64 * 2];

  const int tid = threadIdx.x;
  const int blk = blockIdx.x;
  const int w = tid >> 6;
  const int l = tid & 63;
  const int l15 = l & 15;
  const int lq = l >> 4;
  const int j4 = l15 & 3;

  char* xsb = (char*)xs;
  char* ctb = (char*)ct;
  char* Pb  = (char*)P;
  char* scb = (char*)sc;

  const f32x4 fzero = {0.f, 0.f, 0.f, 0.f};

  // ---- per-block constants
  float cb[4], gg[4], bb[4];
#pragma unroll
  for (int ni = 0; ni < 4; ++ni) {
    int d = w * 64 + ni * 16 + l15;
    cb[ni] = conv_b[d];
    gg[ni] = ln_g[d];
    bb[ni] = ln_b[d];
  }

  // ---- W fragment pipeline: NAMED 2-deep rotation (no indexed array -> no scratch)
  half8 bA[4], bB[4];
  auto loadB = [&](half8* bR, int ks) {
#pragma unroll
    for (int ni = 0; ni < 4; ++ni)
      bR[ni] = *(const half8*)(Wf + (size_t)(((w * 4 + ni) * 32 + ks) * 64 + l) * 8);
  };

  // ---- x prefetch in HALVES: 8 dwordx4 per thread per half (32 VGPRs, reused)
  f32x4 pf[8];
  auto prefetch_half = [&](const float* xg, int h) {
#pragma unroll
    for (int i = 0; i < 4; ++i) {
      int jj = tid + (h * 4 + i) * 512;
      int t = jj >> 6;
      int d8 = jj & 63;
      const f32x4* src = (const f32x4*)(xg + t * HID + d8 * 8);
      pf[2 * i]     = src[0];
      pf[2 * i + 1] = src[1];
    }
  };
  auto write_xs_half = [&](int h) {   // convert fp32 regs -> fp16, store swizzled
#pragma unroll
    for (int i = 0; i < 4; ++i) {
      int jj = tid + (h * 4 + i) * 512;
      int t = jj >> 6;
      int d8 = jj & 63;
      f32x4 f0 = pf[2 * i];
      f32x4 f1 = pf[2 * i + 1];
      half8 hh;
      hh[0] = (_Float16)f0[0]; hh[1] = (_Float16)f0[1]; hh[2] = (_Float16)f0[2]; hh[3] = (_Float16)f0[3];
      hh[4] = (_Float16)f1[0]; hh[5] = (_Float16)f1[1]; hh[6] = (_Float16)f1[2]; hh[7] = (_Float16)f1[3];
      int srow = t + 1;
      *(half8*)(xsb + srow * 1024 + ((d8 * 16) ^ ((srow & 7) << 4))) = hh;
    }
  };

  // ---- block prologue: guard rows + stage chunk 0 + warm W pipeline
  const int chunk0 = blk * CPB;
  if (tid < 128) {
    int r = (tid < 64) ? 0 : 65;
    int g = tid & 63;
    half8 z = {0, 0, 0, 0, 0, 0, 0, 0};
    *(half8*)(xsb + r * 1024 + g * 16) = z;   // swizzle-invariant zeros, written once
  }
  {
    const float* xg0 = x + (size_t)chunk0 * (64 * HID);
    prefetch_half(xg0, 0);
    write_xs_half(0);
    prefetch_half(xg0, 1);
    write_xs_half(1);
  }
  loadB(bA, 0);
  loadB(bB, 1);
  __syncthreads();

  for (int cc = 0; cc < CPB; ++cc) {
    const int chunk = chunk0 + cc;
    const bool haveNext = (cc + 1 < CPB);
    const float* xgn = x + (size_t)(chunk + 1) * (64 * HID);

    // ---------- Phase 1: conv GEMM ct = relu(A[64x1024] @ W[1024x512] + b)
    // A[t][k] = (k<512) ? x[t-1][k] : x[t+1][k-512]  -> xs storage rows t / t+2.
    f32x4 acc[4][4];
#pragma unroll
    for (int mi = 0; mi < 4; ++mi)
#pragma unroll
      for (int ni = 0; ni < 4; ++ni) acc[mi][ni] = fzero;

    {
      auto conv_step = [&](int ks, half8* bR) {
        const int kc2 = (ks & 15) * 64 + lq * 16;
        const int rowoff = (ks < 16) ? 0 : 2;
        half8 a[4];
#pragma unroll
        for (int mi = 0; mi < 4; ++mi) {
          int srow = mi * 16 + l15 + rowoff;
          a[mi] = *(const half8*)(xsb + srow * 1024 + (kc2 ^ ((srow & 7) << 4)));
        }
#pragma unroll
        for (int mi = 0; mi < 4; ++mi)
#pragma unroll
          for (int ni = 0; ni < 4; ++ni)
            acc[mi][ni] = __builtin_amdgcn_mfma_f32_16x16x32_f16(a[mi], bR[ni], acc[mi][ni], 0, 0, 0);
      };
      for (int ks = 0; ks < 30; ks += 2) {
        conv_step(ks, bA);
        loadB(bA, ks + 2);
        conv_step(ks + 1, bB);
        loadB(bB, ks + 3);
      }
      conv_step(30, bA);
      conv_step(31, bB);
    }

    // ---- issue next chunk's x loads, HALF 0 (rows 0..31): covered by
    // epilogue + B1 + scores + B2 + softmax.
    if (haveNext) prefetch_half(xgn, 0);
    __builtin_amdgcn_sched_barrier(0);   // pin issue point

    // ---------- epilogue: bias+relu (kept in acc), ct[key][d] write via 4x4 shfl transpose
#pragma unroll
    for (int mi = 0; mi < 4; ++mi)
#pragma unroll
      for (int ni = 0; ni < 4; ++ni) {
        float v0 = fmaxf(acc[mi][ni][0] + cb[ni], 0.f);
        float v1 = fmaxf(acc[mi][ni][1] + cb[ni], 0.f);
        float v2 = fmaxf(acc[mi][ni][2] + cb[ni], 0.f);
        float v3 = fmaxf(acc[mi][ni][3] + cb[ni], 0.f);
        acc[mi][ni][0] = v0; acc[mi][ni][1] = v1;
        acc[mi][ni][2] = v2; acc[mi][ni][3] = v3;
        float t0 = __shfl_xor(v1, 1);
        float t1 = __shfl_xor(v0, 1);
        float t2 = __shfl_xor(v3, 1);
        float t3 = __shfl_xor(v2, 1);
        if (j4 & 1) { v0 = t0; v2 = t2; } else { v1 = t1; v3 = t3; }
        float u0 = __shfl_xor(v2, 2);
        float u1 = __shfl_xor(v3, 2);
        float u2 = __shfl_xor(v0, 2);
        float u3 = __shfl_xor(v1, 2);
        if (j4 & 2) { v0 = u0; v1 = u1; } else { v2 = u2; v3 = u3; }
        half4 h = {(_Float16)v0, (_Float16)v1, (_Float16)v2, (_Float16)v3};
        int key = mi * 16 + lq * 4 + j4;
        int dbase = w * 64 + ni * 16 + (l15 & ~3);
        *(half4*)(ctb + key * 1024 + ((dbase * 2) ^ ((key & 7) << 4))) = h;
      }
    __syncthreads();   // B1: ct visible

    // ---------- Phase 2: scores^T[key][q] = (ct @ x^T) / sqrt(D)
    {
      const int mt = w & 3;
      const int nt0 = (w >> 2) * 2;
      f32x4 s0 = fzero, s1 = fzero;
      for (int ks = 0; ks < 16; ++ks) {
        int kb = ks * 64 + lq * 16;
        int key = mt * 16 + l15;
        half8 a = *(const half8*)(ctb + key * 1024 + (kb ^ ((key & 7) << 4)));
        int q0 = nt0 * 16 + l15;
        int sr0 = q0 + 1, sr1 = q0 + 17;
        half8 b0 = *(const half8*)(xsb + sr0 * 1024 + (kb ^ ((sr0 & 7) << 4)));
        half8 b1 = *(const half8*)(xsb + sr1 * 1024 + (kb ^ ((sr1 & 7) << 4)));
        s0 = __builtin_amdgcn_mfma_f32_16x16x32_f16(a, b0, s0, 0, 0, 0);
        s1 = __builtin_amdgcn_mfma_f32_16x16x32_f16(a, b1, s1, 0, 0, 0);
      }
      const float scale = 0.04419417382415922f;  // 1/sqrt(512)
#pragma unroll
      for (int r = 0; r < 4; ++r) { s0[r] *= scale; s1[r] *= scale; }
      int gran = mt * 4 + lq;
      int q0 = nt0 * 16 + l15, q1 = q0 + 16;
      *(f32x4*)(scb + q0 * 256 + ((gran * 16) ^ ((q0 & 15) << 4))) = s0;
      *(f32x4*)(scb + q1 * 256 + ((gran * 16) ^ ((q1 & 15) << 4))) = s1;
    }
    __syncthreads();   // B2: sc visible; ct/xs reads done -> both may be overwritten

    // ---------- Phase 3a: softmax rows -> P = softmax + I (fused residual)
    {
      int q = tid >> 3;
      int g = tid & 7;
      f32x4 va = *(const f32x4*)(scb + q * 256 + (((2 * g + 0) * 16) ^ ((q & 15) << 4)));
      f32x4 vb = *(const f32x4*)(scb + q * 256 + (((2 * g + 1) * 16) ^ ((q & 15) << 4)));
      float v[8] = {va[0], va[1], va[2], va[3], vb[0], vb[1], vb[2], vb[3]};
      float m = v[0];
#pragma unroll
      for (int i = 1; i < 8; ++i) m = fmaxf(m, v[i]);
      m = fmaxf(m, __shfl_xor(m, 1));
      m = fmaxf(m, __shfl_xor(m, 2));
      m = fmaxf(m, __shfl_xor(m, 4));
      float s = 0.f;
#pragma unroll
      for (int i = 0; i < 8; ++i) { v[i] = __expf(v[i] - m); s += v[i]; }
      s += __shfl_xor(s, 1);
      s += __shfl_xor(s, 2);
      s += __shfl_xor(s, 4);
      float inv = 1.f / s;
      half8 p;
#pragma unroll
      for (int i = 0; i < 8; ++i) {
        float pv = v[i] * inv + ((g * 8 + i == q) ? 1.f : 0.f);
        p[i] = (_Float16)pv;
      }
      *(half8*)(Pb + q * 128 + ((g * 16) ^ ((q & 7) << 4))) = p;
    }

    // ---------- Phase 3b: ctT[512 d][64 key] into (dead) ct region from live acc
#pragma unroll
    for (int mi = 0; mi < 4; ++mi)
#pragma unroll
      for (int ni = 0; ni < 4; ++ni) {
        int t0 = mi * 16 + lq * 4;
        int d = w * 64 + ni * 16 + l15;
        half4 h = {(_Float16)acc[mi][ni][0], (_Float16)acc[mi][ni][1],
                   (_Float16)acc[mi][ni][2], (_Float16)acc[mi][ni][3]};
        *(half4*)(ctb + d * 128 + ((t0 * 2) ^ ((d & 7) << 4))) = h;
      }

    // ---------- Phase 3c: write x half 0 to xs; issue half 1 (reg reuse)
    if (haveNext) {
      write_xs_half(0);
      prefetch_half(xgn, 1);   // consumed after B4; covered by B3 + PV + LN
    }
    __builtin_amdgcn_sched_barrier(0);
    __syncthreads();   // B3: P, ctT, xs half 0 visible

    // ---------- Phase 4: (P+I) @ ct -> acc REUSED as PV accumulator (64 AGPR total)
#pragma unroll
    for (int mi = 0; mi < 4; ++mi)
#pragma unroll
      for (int ni = 0; ni < 4; ++ni) acc[mi][ni] = fzero;

#pragma unroll
    for (int ks = 0; ks < 2; ++ks) {
      half8 a[4], b[4];
#pragma unroll
      for (int mi = 0; mi < 4; ++mi) {
        int q = mi * 16 + l15;
        a[mi] = *(const half8*)(Pb + q * 128 + (((ks * 4 + lq) * 16) ^ ((q & 7) << 4)));
      }
#pragma unroll
      for (int ni = 0; ni < 4; ++ni) {
        int d = w * 64 + ni * 16 + l15;
        b[ni] = *(const half8*)(ctb + d * 128 + (((ks * 4 + lq) * 16) ^ ((d & 7) << 4)));
      }
#pragma unroll
      for (int mi = 0; mi < 4; ++mi)
#pragma unroll
        for (int ni = 0; ni < 4; ++ni)
          acc[mi][ni] = __builtin_amdgcn_mfma_f32_16x16x32_f16(a[mi], b[ni], acc[mi][ni], 0, 0, 0);
    }

    // per-row LN partial sums over this wave's 64 d-columns
#pragma unroll
    for (int mi = 0; mi < 4; ++mi)
#pragma unroll
      for (int r = 0; r < 4; ++r) {
        float s1 = 0.f, s2 = 0.f;
#pragma unroll
        for (int ni = 0; ni < 4; ++ni) {
          float v = acc[mi][ni][r];
          s1 += v;
          s2 += v * v;
        }
        s1 += __shfl_xor(s1, 1); s2 += __shfl_xor(s2, 1);
        s1 += __shfl_xor(s1, 2); s2 += __shfl_xor(s2, 2);
        s1 += __shfl_xor(s1, 4); s2 += __shfl_xor(s2, 4);
        s1 += __shfl_xor(s1, 8); s2 += __shfl_xor(s2, 8);
        if (l15 == 0) {
          int t = mi * 16 + lq * 4 + r;
          rowpart[(t * 8 + w) * 2 + 0] = s1;
          rowpart[(t * 8 + w) * 2 + 1] = s2;
        }
      }
    __syncthreads();   // B4

    {
      int row = tid >> 3, p = tid & 7;
      float s1 = rowpart[(row * 8 + p) * 2 + 0];
      float s2 = rowpart[(row * 8 + p) * 2 + 1];
      s1 += __shfl_xor(s1, 1); s2 += __shfl_xor(s2, 1);
      s1 += __shfl_xor(s1, 2); s2 += __shfl_xor(s2, 2);
      s1 += __shfl_xor(s1, 4); s2 += __shfl_xor(s2, 4);
      if (p == 0) {
        float mu = s1 * (1.f / 512.f);
        float var = s2 * (1.f / 512.f) - mu * mu;
        mustat[row * 2 + 0] = mu;
        mustat[row * 2 + 1] = rsqrtf(var + 1e-5f);
      }
    }

    // ---------- write x half 1 to xs (visible to next conv after B5)
    if (haveNext) write_xs_half(1);
    __syncthreads();   // B5: mustat + xs half 1 visible

    // pooled[d] = g[d] * (1/64) * sum_q (v[q][d]-mu[q])*rs[q] + b[d]
#pragma unroll
    for (int ni = 0; ni < 4; ++ni) {
      float s = 0.f;
#pragma unroll
      for (int mi = 0; mi < 4; ++mi)
#pragma unroll
        for (int r = 0; r < 4; ++r) {
          int t = mi * 16 + lq * 4 + r;
          s += (acc[mi][ni][r] - mustat[t * 2]) * mustat[t * 2 + 1];
        }
      s += __shfl_xor(s, 16);
      s += __shfl_xor(s, 32);
      if (l < 16) {
        int d = w * 64 + ni * 16 + l;
        out[(size_t)chunk * 512 + d] = gg[ni] * (s * (1.f / 64.f)) + bb[ni];
      }
    }

    // ---------- loop tail: warm W pipeline for next chunk (acc dead, pf dead)
    if (haveNext) {
      loadB(bA, 0);
      loadB(bB, 1);
    }
  }
}

extern "C" void kernel_launch(void* const* d_in, const int* in_sizes, int n_in,
                              void* d_out, int out_size, void* d_ws, size_t ws_size,
                              hipStream_t stream) {
  const float* x      = (const float*)d_in[0];
  const float* conv_w = (const float*)d_in[1];
  const float* conv_b = (const float*)d_in[2];
  const float* ln_g   = (const float*)d_in[3];
  const float* ln_b   = (const float*)d_in[4];
  float* out = (float*)d_out;
  _Float16* Wf = (_Float16*)d_ws;   // 512*1024 fp16 = 1 MB, fragment-ordered

  prep_w_kernel<<<(HID * HID * 2 + 255) / 256, 256, 0, stream>>>(conv_w, Wf);
  fused_kernel<<<NBLK, 512, 0, stream>>>(x, Wf, conv_b, ln_g, ln_b, out);
}